// Round 2
// baseline (193.683 us; speedup 1.0000x reference)
//
#include <hip/hip_runtime.h>
#include <hip/hip_fp16.h>
#include <cstdint>

#define T_DIM 64
#define IN_DIM 4100
#define OUT_DIM 12288
#define G_DIM 820
#define KCODE 256
#define GRP 5
#define KP 6560          /* padded K' = 820 groups * 8 */
#define CHUNKS 41        /* 20 groups per chunk */
#define CH_G 20
#define CH_K 160         /* 20*8 padded k per chunk */
#define KSPLIT 4
#define NBLK 192         /* 12288 / 64 */
#define LDS_STRIDE 168   /* 160 + 8 pad halfs; 336B = 21 dwords -> b128-friendly */

typedef _Float16 f16x8 __attribute__((ext_vector_type(8)));
typedef float f32x4 __attribute__((ext_vector_type(4)));

__device__ unsigned g_amax[2];                        // [0]=absmax(x) bits, [1]=absmax(cb) bits
__device__ float g_cbf[2 * KCODE * GRP];              // codebooks canonicalized to f32
__device__ __align__(16) _Float16 g_xsafe[T_DIM * KP];// fp16-quantized x, group-padded layout
__device__ float g_part[KSPLIT * T_DIM * OUT_DIM];    // K-split partial sums

__global__ void init_kernel() {
    if (threadIdx.x == 0) g_amax[0] = 0u;
}

__global__ void absmax_x_kernel(const float* __restrict__ x) {
    int tid = threadIdx.x;
    float m = 0.f;
    for (int i = blockIdx.x * 256 + tid; i < T_DIM * IN_DIM; i += gridDim.x * 256)
        m = fmaxf(m, fabsf(x[i]));
    for (int off = 32; off > 0; off >>= 1)
        m = fmaxf(m, __shfl_down(m, off));
    __shared__ float sm[4];
    if ((tid & 63) == 0) sm[tid >> 6] = m;
    __syncthreads();
    if (tid == 0) {
        m = fmaxf(fmaxf(sm[0], sm[1]), fmaxf(sm[2], sm[3]));
        atomicMax(&g_amax[0], __float_as_uint(m));
    }
}

// Harness dtype contract doesn't list float16: codebooks may arrive as f32.
// Detect from the bits: f32 exponent field of |v|~0.05 is ~120-125; if the
// buffer is packed fp16 pairs, bits 30:23 hold the 2nd half's exp+mantissa
// (~64-95 for this magnitude). Threshold 100. Canonicalize to f32 + absmax.
__global__ void prep_cb_kernel(const void* __restrict__ cbraw) {
    int tid = threadIdx.x;
    unsigned u0 = *(const unsigned*)cbraw;
    int e = (u0 >> 23) & 0xFF;
    bool is_f32 = (e >= 100);
    float m = 0.f;
    for (int i = tid; i < 2 * KCODE * GRP; i += 256) {
        float v = is_f32 ? ((const float*)cbraw)[i]
                         : (float)((const _Float16*)cbraw)[i];
        g_cbf[i] = v;
        m = fmaxf(m, fabsf(v));
    }
    for (int off = 32; off > 0; off >>= 1)
        m = fmaxf(m, __shfl_down(m, off));
    __shared__ float sm[4];
    if ((tid & 63) == 0) sm[tid >> 6] = m;
    __syncthreads();
    if (tid == 0) {
        m = fmaxf(fmaxf(sm[0], sm[1]), fmaxf(sm[2], sm[3]));
        g_amax[1] = __float_as_uint(m);
    }
}

// x_safe[t][g*8+j] = fp16(x[t][g*5+j] / x_max) for j<5, else 0
__global__ void quantize_kernel(const float* __restrict__ x) {
    int i = blockIdx.x * 256 + threadIdx.x;
    if (i >= T_DIM * KP) return;
    float xm = fmaxf(__uint_as_float(g_amax[0]), 1.0f) * 8.0f;
    int t = i / KP;
    int col = i - t * KP;
    int g = col >> 3, j = col & 7;
    _Float16 v = (_Float16)0.f;
    if (j < GRP) v = (_Float16)(x[t * IN_DIM + g * GRP + j] / xm);
    g_xsafe[i] = v;
}

// GEMM: out[t][o] = sum_k x_safe[t][k] * W[o][k], W gathered from codebooks.
// Block: 256 thr = 4 waves; tile 64(T) x 64(O); K-split x4 over 41 chunks of 20 groups.
__global__ void __launch_bounds__(256) main_kernel(const int* __restrict__ indices) {
    __shared__ alignas(16) _Float16 x_lds[64 * LDS_STRIDE];
    __shared__ alignas(16) _Float16 w_lds[64 * LDS_STRIDE];
    __shared__ f16x8 cb_sh[2 * KCODE];   // codebook entries padded to 8 halfs (3 zeros)

    int tid = threadIdx.x;
    int nb = blockIdx.x % NBLK;
    int ksp = blockIdx.x / NBLK;
    int n_base = nb * 64;

    float cbm = fmaxf(__uint_as_float(g_amax[1]), 1.0f);
    for (int e = tid; e < 2 * KCODE; e += 256) {
        f16x8 v = {};
        #pragma unroll
        for (int j = 0; j < GRP; ++j)
            v[j] = (_Float16)(g_cbf[e * GRP + j] / cbm);
        cb_sh[e] = v;
    }
    __syncthreads();

    f32x4 acc[4] = {};

    int c0 = (CHUNKS * ksp) / KSPLIT;
    int c1 = (CHUNKS * (ksp + 1)) / KSPLIT;

    int wid = tid >> 6, lane = tid & 63;
    int q = lane >> 4, r16 = lane & 15;

    for (int c = c0; c < c1; ++c) {
        int k0 = c * CH_K;
        int g0 = c * CH_G;
        // stage x chunk: 64 rows x 160 halfs (16B segments)
        for (int s = tid; s < 64 * 20; s += 256) {
            int m = s / 20, seg = s - m * 20;
            *(uint4*)&x_lds[m * LDS_STRIDE + seg * 8] =
                *(const uint4*)&g_xsafe[m * KP + k0 + seg * 8];
        }
        // gather W chunk: 64 o x 20 groups
        for (int p = tid; p < 64 * 20; p += 256) {
            int ol = p / 20, gl = p - ol * 20;
            const int2 idx = *(const int2*)&indices[(size_t)(n_base + ol) * (G_DIM * 2)
                                                    + (size_t)(g0 + gl) * 2];
            f16x8 w = cb_sh[idx.x] + cb_sh[KCODE + idx.y];   // fp16 add, matches ref
            *(f16x8*)&w_lds[ol * LDS_STRIDE + gl * 8] = w;
        }
        __syncthreads();
        #pragma unroll
        for (int kk = 0; kk < 5; ++kk) {
            int kb = kk * 32 + q * 8;
            f16x8 a = *(const f16x8*)&x_lds[(wid * 16 + r16) * LDS_STRIDE + kb];
            #pragma unroll
            for (int nt = 0; nt < 4; ++nt) {
                f16x8 b = *(const f16x8*)&w_lds[(nt * 16 + r16) * LDS_STRIDE + kb];
                acc[nt] = __builtin_amdgcn_mfma_f32_16x16x32_f16(a, b, acc[nt], 0, 0, 0);
            }
        }
        __syncthreads();
    }

    // C/D layout: col = lane&15 (o), row = (lane>>4)*4 + reg (t within 16-tile)
    float* outp = g_part + (size_t)ksp * (T_DIM * OUT_DIM);
    #pragma unroll
    for (int nt = 0; nt < 4; ++nt) {
        #pragma unroll
        for (int rr = 0; rr < 4; ++rr) {
            int t = wid * 16 + q * 4 + rr;
            int o = n_base + nt * 16 + r16;
            outp[t * OUT_DIM + o] = acc[nt][rr];
        }
    }
}

__global__ void finalize_kernel(const float* __restrict__ scales, float* __restrict__ out) {
    int i = blockIdx.x * 256 + threadIdx.x;
    if (i >= T_DIM * OUT_DIM) return;
    float xm = fmaxf(__uint_as_float(g_amax[0]), 1.0f) * 8.0f;
    float cbm = fmaxf(__uint_as_float(g_amax[1]), 1.0f);
    int o = i % OUT_DIM;
    float v = g_part[i] + g_part[T_DIM * OUT_DIM + i]
            + g_part[2 * T_DIM * OUT_DIM + i] + g_part[3 * T_DIM * OUT_DIM + i];
    v = v * xm * cbm * scales[o];
    if (!isfinite(v)) v = 0.f;
    out[i] = v;
}

extern "C" void kernel_launch(void* const* d_in, const int* in_sizes, int n_in,
                              void* d_out, int out_size, void* d_ws, size_t ws_size,
                              hipStream_t stream) {
    const float* x = (const float*)d_in[0];
    const int* indices = (const int*)d_in[1];
    const void* cbraw = (const void*)d_in[2];
    const float* scales = (const float*)d_in[3];
    float* out = (float*)d_out;
    (void)d_ws; (void)ws_size; (void)n_in; (void)in_sizes; (void)out_size;

    init_kernel<<<1, 64, 0, stream>>>();
    absmax_x_kernel<<<512, 256, 0, stream>>>(x);
    prep_cb_kernel<<<1, 256, 0, stream>>>(cbraw);
    quantize_kernel<<<(T_DIM * KP + 255) / 256, 256, 0, stream>>>(x);
    main_kernel<<<NBLK * KSPLIT, 256, 0, stream>>>(indices);
    finalize_kernel<<<(T_DIM * OUT_DIM + 255) / 256, 256, 0, stream>>>(scales, out);
}

// Round 4
// 146.606 us; speedup vs baseline: 1.3211x; 1.3211x over previous
//
#include <hip/hip_runtime.h>
#include <hip/hip_fp16.h>
#include <cstdint>

#define T_DIM 64
#define IN_DIM 4100
#define OUT_DIM 12288
#define G_DIM 820
#define KCODE 256
#define GRP 5
#define KP 6560          /* padded K' = 820 groups * 8 */
#define KB32 205         /* KP/32 k-blocks of 32 */
#define CHUNKS 41        /* 20 groups per chunk */
#define CH_G 20
#define CH_K 160
#define KSPLIT 4
#define NBLK 192         /* 12288 / 64 */
#define LDS_STRIDE 168   /* 160 + 8 pad halfs; 21 quads/row (odd -> good spread) */

typedef _Float16 f16x8 __attribute__((ext_vector_type(8)));
typedef float f32x4 __attribute__((ext_vector_type(4)));

__device__ float g_pmax[256];                            // per-block |x| partial max
__device__ float g_cbmax;                                // clamped cb_max
__device__ float g_xmax;                                 // clamped x_max*8
__device__ __align__(16) _Float16 g_cbq[2 * KCODE * 8];  // padded, pre-scaled fp16 cb
__device__ __align__(16) _Float16 g_xA[4 * KB32 * 64 * 8]; // A-frags, MFMA lane order
__device__ __align__(16) float g_part[KSPLIT * T_DIM * OUT_DIM];

__device__ __forceinline__ float block_reduce_max(float m, float* sm) {
    for (int off = 32; off > 0; off >>= 1)
        m = fmaxf(m, __shfl_down(m, off));
    int tid = threadIdx.x;
    if ((tid & 63) == 0) sm[tid >> 6] = m;
    __syncthreads();
    float r = fmaxf(fmaxf(sm[0], sm[1]), fmaxf(sm[2], sm[3]));
    __syncthreads();
    return r;
}

// K1: per-block |x| partial max (256 blocks); block 0 canonicalizes + scales cb.
__global__ void __launch_bounds__(256) k1_absmax_cb(const float* __restrict__ x,
                                                    const void* __restrict__ cbraw) {
    __shared__ float sm[4];
    int tid = threadIdx.x, bid = blockIdx.x;
    float m = 0.f;
    for (int i = bid * 256 + tid; i < T_DIM * IN_DIM; i += 256 * 256)
        m = fmaxf(m, fabsf(x[i]));
    float r = block_reduce_max(m, sm);
    if (tid == 0) g_pmax[bid] = r;

    if (bid == 0) {
        // dtype probe (verified R2): fp16 codebooks may arrive upcast to f32.
        unsigned u0 = *(const unsigned*)cbraw;
        bool is_f32 = (((u0 >> 23) & 0xFF) >= 100);
        float mm = 0.f;
        for (int i = tid; i < 2 * KCODE * GRP; i += 256) {
            float v = is_f32 ? ((const float*)cbraw)[i]
                             : (float)((const _Float16*)cbraw)[i];
            mm = fmaxf(mm, fabsf(v));
        }
        float cbm = fmaxf(block_reduce_max(mm, sm), 1.0f);
        if (tid == 0) g_cbmax = cbm;
        for (int e = tid; e < 2 * KCODE; e += 256) {
            f16x8 v = {};
            #pragma unroll
            for (int j = 0; j < GRP; ++j) {
                float w = is_f32 ? ((const float*)cbraw)[e * GRP + j]
                                 : (float)((const _Float16*)cbraw)[e * GRP + j];
                v[j] = (_Float16)(w / cbm);
            }
            *(f16x8*)&g_cbq[e * 8] = v;
        }
    }
}

// K2: reduce partials -> xm; quantize x straight into MFMA-A-fragment order.
// g_xA[((t16*KB32 + kb32)*64 + lane)*8 + j] = fp16(x[t16*16+(lane&15)]
//                                                   [(kb32*4+(lane>>4))*5 + j] / xm), j<5
__global__ void __launch_bounds__(256) k2_quant(const float* __restrict__ x) {
    __shared__ float sm[4];
    int tid = threadIdx.x;
    float xm = fmaxf(block_reduce_max(g_pmax[tid], sm), 1.0f) * 8.0f;
    if (blockIdx.x == 0 && tid == 0) g_xmax = xm;

    int gt = blockIdx.x * 256 + tid;        // [0, 205*256) == 4*KB32*64
    int lane = gt & 63;
    int rest = gt >> 6;                     // t16*KB32 + kb32
    int kb32 = rest % KB32;
    int t16 = rest / KB32;
    int r16 = lane & 15, q = lane >> 4;
    int t = t16 * 16 + r16;
    int g = kb32 * 4 + q;
    const float* xp = x + (size_t)t * IN_DIM + g * GRP;
    f16x8 v = {};
    #pragma unroll
    for (int j = 0; j < GRP; ++j) v[j] = (_Float16)(xp[j] / xm);
    *(f16x8*)&g_xA[(size_t)gt * 8] = v;
}

// K3: GEMM. 768 blocks (192 o-tiles x KSPLIT=4), 256 thr = 4 waves.
// Tile 64(T)x64(O); A-frags direct from global (coalesced, L2); W gathered to LDS.
__global__ void __launch_bounds__(256) k3_gemm(const int* __restrict__ indices) {
    __shared__ alignas(16) _Float16 w_lds[64 * LDS_STRIDE];
    __shared__ f16x8 cb_sh[2 * KCODE];

    int tid = threadIdx.x;
    int nb = blockIdx.x % NBLK;
    int ksp = blockIdx.x / NBLK;
    int n_base = nb * 64;

    for (int e = tid; e < 2 * KCODE; e += 256)
        cb_sh[e] = *(const f16x8*)&g_cbq[e * 8];

    // per-thread staging slots: 64 o-rows x 20 groups = 5*256
    int sro[5], sgl[5];
    #pragma unroll
    for (int j = 0; j < 5; ++j) {
        int s = tid + j * 256;
        sro[j] = s / 20; sgl[j] = s - sro[j] * 20;
    }

    const int c0 = (CHUNKS * ksp) / KSPLIT;
    const int c1 = (CHUNKS * (ksp + 1)) / KSPLIT;
    const int wid = tid >> 6, lane = tid & 63;
    const int q = lane >> 4, r16 = lane & 15;

    f32x4 acc[4] = {};
    int2 idxr[5];
    uint4 ar[5];
    auto prefetch = [&](int c) {
        int g0 = c * CH_G, kb = c * 5;
        #pragma unroll
        for (int j = 0; j < 5; ++j) {
            ar[j] = *(const uint4*)&g_xA[(size_t)((wid * KB32 + kb + j) * 64 + lane) * 8];
            idxr[j] = *(const int2*)&indices[(size_t)(n_base + sro[j]) * (G_DIM * 2)
                                             + (size_t)(g0 + sgl[j]) * 2];
        }
    };

    prefetch(c0);
    __syncthreads();   // cb_sh ready

    for (int c = c0; c < c1; ++c) {
        // stage W tile from prefetched indices (gather + fp16 add, matches ref)
        #pragma unroll
        for (int j = 0; j < 5; ++j) {
            f16x8 w = cb_sh[idxr[j].x] + cb_sh[KCODE + idxr[j].y];
            *(f16x8*)&w_lds[sro[j] * LDS_STRIDE + sgl[j] * 8] = w;
        }
        uint4 acur[5];
        #pragma unroll
        for (int j = 0; j < 5; ++j) acur[j] = ar[j];
        __syncthreads();            // W tile ready
        if (c + 1 < c1) prefetch(c + 1);   // next A/idx fly under MFMA phase
        #pragma unroll
        for (int kk = 0; kk < 5; ++kk) {
            f16x8 a = *(f16x8*)&acur[kk];
            #pragma unroll
            for (int nt = 0; nt < 4; ++nt) {
                f16x8 b = *(const f16x8*)&w_lds[(nt * 16 + r16) * LDS_STRIDE + kk * 32 + q * 8];
                acc[nt] = __builtin_amdgcn_mfma_f32_16x16x32_f16(a, b, acc[nt], 0, 0, 0);
            }
        }
        __syncthreads();            // W tile consumed
    }

    // C/D: col = lane&15 (o), row = (lane>>4)*4 + reg (t)   [verified R2]
    float* outp = g_part + (size_t)ksp * (T_DIM * OUT_DIM);
    #pragma unroll
    for (int nt = 0; nt < 4; ++nt) {
        #pragma unroll
        for (int rr = 0; rr < 4; ++rr) {
            int t = wid * 16 + q * 4 + rr;
            int o = n_base + nt * 16 + r16;
            outp[t * OUT_DIM + o] = acc[nt][rr];
        }
    }
}

// K4: sum K-split partials, scale by xm*cbm*scales[o], nan_to_num, store float4.
__global__ void __launch_bounds__(256) k4_final(const float* __restrict__ scales,
                                                float* __restrict__ out) {
    int i4 = blockIdx.x * 256 + threadIdx.x;
    if (i4 >= T_DIM * OUT_DIM / 4) return;
    float s = g_xmax * g_cbmax;
    const f32x4* p = (const f32x4*)g_part;
    const int Q = T_DIM * OUT_DIM / 4;
    f32x4 v0 = p[i4], v1 = p[Q + i4], v2 = p[2 * Q + i4], v3 = p[3 * Q + i4];
    int o4 = i4 % (OUT_DIM / 4);
    f32x4 sc = *(const f32x4*)&scales[o4 * 4];
    f32x4 r;
    #pragma unroll
    for (int j = 0; j < 4; ++j) {
        float v = (v0[j] + v1[j] + v2[j] + v3[j]) * s * sc[j];
        if (!isfinite(v)) v = 0.f;
        r[j] = v;
    }
    ((f32x4*)out)[i4] = r;
}

extern "C" void kernel_launch(void* const* d_in, const int* in_sizes, int n_in,
                              void* d_out, int out_size, void* d_ws, size_t ws_size,
                              hipStream_t stream) {
    const float* x = (const float*)d_in[0];
    const int* indices = (const int*)d_in[1];
    const void* cbraw = (const void*)d_in[2];
    const float* scales = (const float*)d_in[3];
    float* out = (float*)d_out;
    (void)d_ws; (void)ws_size; (void)n_in; (void)in_sizes; (void)out_size;

    k1_absmax_cb<<<256, 256, 0, stream>>>(x, cbraw);
    k2_quant<<<205, 256, 0, stream>>>(x);
    k3_gemm<<<NBLK * KSPLIT, 256, 0, stream>>>(indices);
    k4_final<<<T_DIM * OUT_DIM / 4 / 256, 256, 0, stream>>>(scales, out);
}